// Round 16
// baseline (11376.763 us; speedup 1.0000x reference)
//
#include <hip/hip_runtime.h>

// CustomRNN (GRU, SEQ=2048, B=256, D=512) + FC(1000) + log_softmax over batch axis.
//
// R16 = R15's gru_rec (PASSING, 8.22ms, byte-identical) + gate_gemm RESTRUCTURED:
//   BM=64 x BN=1536: block owns ALL 1536 output cols for its 64 rows -> A (x fp32,
//   1.07GB) is read from HBM exactly ONCE (old 128x128 tiling re-read it up to 12x;
//   R15 proved consumer-reordering doesn't fix it). A lives in LDS (64x512 bf16,
//   66.5KB); B (WT, 1.5MB) stays L2-resident and is loaded per-wave per 64-col chunk
//   (16 cols x K=512 = 64 VGPR); 64 MFMAs per wave per chunk; ONE syncthreads/block.
//   Fragment conventions identical to the proven kernels (A-row=l15, B-col=l15,
//   C row=l4*4+q, col=l15).

typedef unsigned short ushort_t;
typedef unsigned int uint_t;
typedef __bf16 bf16_t;
typedef bf16_t bf16x8 __attribute__((ext_vector_type(8)));
typedef float f32x4 __attribute__((ext_vector_type(4)));
typedef uint_t u32x4 __attribute__((ext_vector_type(4)));

__device__ __forceinline__ ushort_t f2bf(float f) {
  uint_t u = __float_as_uint(f);
  u += 0x7FFFu + ((u >> 16) & 1u);   // round-to-nearest-even
  return (ushort_t)(u >> 16);
}
__device__ __forceinline__ float bfu2f(uint_t h) { return __uint_as_float(h << 16); }

// TCC atomic add WITH return (waits). RMW -> always served coherently at the TCC.
__device__ __forceinline__ uint_t atom_add_ret(uint_t* p, uint_t v) {
  uint_t old;
  asm volatile("global_atomic_add %0, %1, %2, off sc0\n\t"
               "s_waitcnt vmcnt(0)"
               : "=v"(old) : "v"(p), "v"(v) : "memory");
  return old;
}
// Fire-and-forget atomic add (no return -> no wait).
__device__ __forceinline__ void atom_add_noret(uint_t* p, uint_t v) {
  asm volatile("global_atomic_add %0, %1, off" :: "v"(p), "v"(v) : "memory");
}

// ---------------------------------------------------------------- prep
__global__ __launch_bounds__(256) void prep_kernel(
    const float* __restrict__ Wz, const float* __restrict__ Wr, const float* __restrict__ Wh,
    const float* __restrict__ Uz, const float* __restrict__ Ur, const float* __restrict__ Uh,
    const float* __restrict__ bz, const float* __restrict__ buz,
    const float* __restrict__ br, const float* __restrict__ bur,
    const float* __restrict__ bh, const float* __restrict__ buh,
    ushort_t* __restrict__ UT, ushort_t* __restrict__ WT, float* __restrict__ gbias)
{
  const int idx = blockIdx.x * 256 + threadIdx.x;  // exactly 786432 threads
  {
    const int gate = idx >> 18, n = (idx >> 9) & 511, k = idx & 511;
    const float* U = (gate == 0) ? Uz : (gate == 1 ? Ur : Uh);
    UT[idx] = f2bf(U[k * 512 + n]);                 // UT[gate][n][k] = U[k][n]
  }
  {
    const int n = idx >> 9, k = idx & 511;
    const int gate = n >> 9, nn = n & 511;
    const float* W = (gate == 0) ? Wz : (gate == 1 ? Wr : Wh);
    WT[idx] = f2bf(W[k * 512 + nn]);                // WT[n][k] = W[k][n]
  }
  if (idx < 1536) {
    const int gate = idx >> 9, nn = idx & 511;
    gbias[idx] = (gate == 0) ? (bz[nn] + buz[nn])
               : (gate == 1) ? (br[nn] + bur[nn])
                             : (bh[nn] + buh[nn]);
  }
}

// ---------------------------------------------------------------- gate GEMM (A-read-once)
// Block = 64 rows x ALL 1536 cols. A staged once to LDS; B per-wave from L2.
__global__ __launch_bounds__(256) void gate_gemm(
    const float* __restrict__ x,
    const ushort_t* __restrict__ WT,     // [1536 n][512 k] bf16
    const float* __restrict__ gbias,
    ushort_t* __restrict__ gout,         // [M][1536]
    int mtiles)                          // = M/64 (unused bound check only)
{
  __shared__ ushort_t A_sh[64 * 520];    // 64 rows x 512 K bf16, +8 pad
  const int bid = blockIdx.x;
  (void)mtiles;
  const int mrow0 = bid * 64;
  const int tid = threadIdx.x;
  const int wid = tid >> 6;
  const int lane = tid & 63;
  const int l15 = lane & 15, l4 = lane >> 4;

  // ---- A load: 64 x 512 fp32 -> bf16 -> LDS. thread: row = tid>>2, 128-col strip.
  {
    const int r = tid >> 2, cb = (tid & 3) * 128;
    const float* src = &x[(size_t)(mrow0 + r) * 512 + cb];
    ushort_t* dst = &A_sh[r * 520 + cb];
#pragma unroll
    for (int i = 0; i < 32; ++i) {
      const float4 v = ((const float4*)src)[i];
      ushort4 hv;
      hv.x = f2bf(v.x); hv.y = f2bf(v.y); hv.z = f2bf(v.z); hv.w = f2bf(v.w);
      ((ushort4*)dst)[i] = hv;
    }
  }
  __syncthreads();

  // ---- 24 chunks of 64 cols; wave w owns the 16-col subtile w of each chunk.
  for (int nc = 0; nc < 24; ++nc) {
    const int col = nc * 64 + wid * 16 + l15;
    bf16x8 Bv[16];
    {
      const size_t bbase = (size_t)col * 512 + (size_t)(l4 * 8);
#pragma unroll
      for (int k = 0; k < 16; ++k) Bv[k] = *(const bf16x8*)&WT[bbase + (size_t)k * 32];
    }
    f32x4 acc[4];
    const f32x4 vzero = {0.f, 0.f, 0.f, 0.f};
#pragma unroll
    for (int rt = 0; rt < 4; ++rt) acc[rt] = vzero;
#pragma unroll
    for (int ks = 0; ks < 16; ++ks) {
#pragma unroll
      for (int rt = 0; rt < 4; ++rt) {
        const bf16x8 a = *(const bf16x8*)&A_sh[(rt * 16 + l15) * 520 + ks * 32 + l4 * 8];
        acc[rt] = __builtin_amdgcn_mfma_f32_16x16x32_bf16(a, Bv[ks], acc[rt], 0, 0, 0);
      }
    }
    const float bv = gbias[col];
#pragma unroll
    for (int rt = 0; rt < 4; ++rt) {
#pragma unroll
      for (int q = 0; q < 4; ++q)
        gout[(size_t)(mrow0 + rt * 16 + l4 * 4 + q) * 1536 + col] = f2bf(acc[rt][q] + bv);
    }
  }
}

// ---------------------------------------------------------------- XCD-local group barrier
// Monotone counter; arrival = non-blocking add, wait = poll RMW until ctr >= 16*n.
__device__ __forceinline__ bool group_barrier(uint_t* ctr, uint_t target, int tid, int* s_dead) {
  asm volatile("s_waitcnt vmcnt(0)" ::: "memory");  // own stores committed to L2
  __syncthreads();                                   // all waves drained
  if (tid == 0) {
    atom_add_noret(ctr, 1u);
    int cnt = 0;
    for (;;) {
      const uint_t seen = atom_add_ret(ctr, 0u);     // RMW -> always served at TCC
      if (seen >= target) break;
      __builtin_amdgcn_s_sleep(1);
      if (++cnt > (1 << 15)) { *s_dead = 1; break; } // co-location broken: fast-fail
    }
  }
  __syncthreads();
  return *s_dead != 0;
}

// Stage a [16 rows][512] bf16 tile (16 KB) from global (shared L2) into LDS.
// sc0 loads bypass the (possibly stale) L1; ends with vmcnt(0).
// Chunk index rotated by j*64 (spread first-touch lines across the group).
__device__ __forceinline__ void stage16x512(const ushort_t* __restrict__ src, int g, int j,
                                            ushort_t* dst_lds, int tid) {
  const ushort_t* p[4];
  int ridx[4];
#pragma unroll
  for (int k = 0; k < 4; ++k) {
    const int idx = (tid + (k << 8) + j * 64) & 1023;
    ridx[k] = idx;
    const int r = idx >> 6, kc = idx & 63;
    p[k] = src + (((g * 16 + r) << 9) + kc * 8);
  }
  u32x4 v0, v1, v2, v3;
  asm volatile(
      "global_load_dwordx4 %0, %4, off sc0\n\t"
      "global_load_dwordx4 %1, %5, off sc0\n\t"
      "global_load_dwordx4 %2, %6, off sc0\n\t"
      "global_load_dwordx4 %3, %7, off sc0\n\t"
      "s_waitcnt vmcnt(0)"
      : "=&v"(v0), "=&v"(v1), "=&v"(v2), "=&v"(v3)
      : "v"(p[0]), "v"(p[1]), "v"(p[2]), "v"(p[3])
      : "memory");
#pragma unroll
  for (int k = 0; k < 4; ++k) {
    const int r = ridx[k] >> 6, kc = ridx[k] & 63;
    *(u32x4*)&dst_lds[r * 520 + kc * 8] = (k == 0) ? v0 : (k == 1) ? v1 : (k == 2) ? v2 : v3;
  }
}

// ---------------------------------------------------------------- persistent GRU recurrence
__global__ __launch_bounds__(256, 1) void gru_rec(
    const ushort_t* __restrict__ UT,     // [3][512 n][512 k] bf16
    const ushort_t* __restrict__ gates,  // [Tc][256][1536] bf16
    ushort_t* __restrict__ h_buf,        // [256][512] bf16
    ushort_t* __restrict__ rh_buf,       // [256][512] bf16
    float* __restrict__ h_state,         // [256][512] fp32
    uint_t* __restrict__ bars,
    int Tc, int first)
{
  __shared__ ushort_t h_st[16 * 520];
  __shared__ float z_sh[512];
  __shared__ float hown[512];
  __shared__ float red[512];
  __shared__ int s_dead;

  const int tid = threadIdx.x;
  const int bid = blockIdx.x;
  const int g = bid & 15;
  const int j = bid >> 4;
  const int wid = tid >> 6;
  const int lane = tid & 63;
  const int l15 = lane & 15;
  const int l4 = lane >> 4;
  if (tid == 0) s_dead = 0;

  uint_t* ctr = bars + g * 64;          // one counter per group, own cacheline
  uint_t nbar = 0;

  const int p1gate = wid >> 1;  // phase1: waves 0,1 -> z ; waves 2,3 -> r
  const int p1nt = wid & 1;
  const int p2nt = wid >> 1;    // phase2 subtile
  const int p2kh = wid & 1;     // phase2 K half

  // U fragments persistent in registers
  bf16x8 UB[16];
  {
    const size_t base = (size_t)((p1gate << 9) + j * 32 + p1nt * 16 + l15) * 512 + (size_t)(l4 * 8);
#pragma unroll
    for (int kk = 0; kk < 16; ++kk) UB[kk] = *(const bf16x8*)&UT[base + (size_t)kk * 32];
  }
  bf16x8 UH[8];
  {
    const size_t base = (size_t)(1024 + j * 32 + p2nt * 16 + l15) * 512 + (size_t)(p2kh * 256 + l4 * 8);
#pragma unroll
    for (int kk = 0; kk < 8; ++kk) UH[kk] = *(const bf16x8*)&UT[base + (size_t)kk * 32];
  }

  if (first) {
    for (int i = tid; i < 512; i += 256) {
      const int r = i >> 5, c = i & 31;
      h_buf[((g * 16 + r) << 9) + j * 32 + c] = 0;
      hown[i] = 0.f;
    }
  } else {
    for (int i = tid; i < 512; i += 256) {
      const int r = i >> 5, c = i & 31;
      hown[i] = h_state[((g * 16 + r) << 9) + j * 32 + c];
    }
  }
  if (group_barrier(ctr, (++nbar) * 16, tid, &s_dead)) return;

  const int colg1 = j * 32 + p1nt * 16 + l15;
  const int colg2 = j * 32 + p2nt * 16 + l15;

  // gate pipeline: n* prefetched as PLAIN compiler-tracked loads at phase-2 start
  // of the previous step; copied to c* at phase-1 top (compiler inserts the wait).
  uint_t c1u[4], c2u[4], n1u[4], n2u[4];
  {
    const size_t gb = (size_t)(g * 16) * 1536;
#pragma unroll
    for (int q = 0; q < 4; ++q) {
      n1u[q] = gates[gb + (size_t)(l4 * 4 + q) * 1536 + (p1gate << 9) + colg1];
      n2u[q] = gates[gb + (size_t)(l4 * 4 + q) * 1536 + 1024 + colg2];
    }
  }

  for (int tt = 0; tt < Tc; ++tt) {
    // ---- phase 1: z, r from h
    stage16x512(h_buf, g, j, h_st, tid);
    __syncthreads();
#pragma unroll
    for (int q = 0; q < 4; ++q) { c1u[q] = n1u[q]; c2u[q] = n2u[q]; }
    {
      const ushort_t* ap = &h_st[l15 * 520 + l4 * 8];
      f32x4 a0 = {0.f, 0.f, 0.f, 0.f}, a1 = {0.f, 0.f, 0.f, 0.f};
#pragma unroll
      for (int kk = 0; kk < 16; kk += 2) {
        a0 = __builtin_amdgcn_mfma_f32_16x16x32_bf16(*(const bf16x8*)(ap + kk * 32), UB[kk], a0, 0, 0, 0);
        a1 = __builtin_amdgcn_mfma_f32_16x16x32_bf16(*(const bf16x8*)(ap + kk * 32 + 32), UB[kk + 1], a1, 0, 0, 0);
      }
      const f32x4 acc = a0 + a1;
      const int lc = p1nt * 16 + l15;
#pragma unroll
      for (int q = 0; q < 4; ++q) {
        const int row = l4 * 4 + q;
        const float pre = acc[q] + bfu2f(c1u[q]);
        const float s = 1.f / (1.f + __expf(-pre));
        if (p1gate == 0) z_sh[row * 32 + lc] = s;
        else rh_buf[((g * 16 + row) << 9) + j * 32 + lc] = f2bf(s * hown[row * 32 + lc]);
      }
    }
    if (group_barrier(ctr, (++nbar) * 16, tid, &s_dead)) break;

    // ---- phase 2: h~ from (r*h), h update
    stage16x512(rh_buf, g, j, h_st, tid);
    __syncthreads();
    // prefetch next step's gates NOW (plain loads): they complete under the MFMA /
    // epilogue, so the pre-barrier vmcnt(0) and the poll carry no outstanding loads.
    if (tt + 1 < Tc) {
      const size_t gb = (size_t)((size_t)(tt + 1) * 256 + g * 16) * 1536;
#pragma unroll
      for (int q = 0; q < 4; ++q) {
        n1u[q] = gates[gb + (size_t)(l4 * 4 + q) * 1536 + (p1gate << 9) + colg1];
        n2u[q] = gates[gb + (size_t)(l4 * 4 + q) * 1536 + 1024 + colg2];
      }
    }
    {
      const ushort_t* ap = &h_st[l15 * 520 + p2kh * 256 + l4 * 8];
      f32x4 a0 = {0.f, 0.f, 0.f, 0.f}, a1 = {0.f, 0.f, 0.f, 0.f};
#pragma unroll
      for (int kk = 0; kk < 8; kk += 2) {
        a0 = __builtin_amdgcn_mfma_f32_16x16x32_bf16(*(const bf16x8*)(ap + kk * 32), UH[kk], a0, 0, 0, 0);
        a1 = __builtin_amdgcn_mfma_f32_16x16x32_bf16(*(const bf16x8*)(ap + kk * 32 + 32), UH[kk + 1], a1, 0, 0, 0);
      }
      const f32x4 acc = a0 + a1;
      if (p2kh == 1) {
#pragma unroll
        for (int q = 0; q < 4; ++q) red[p2nt * 256 + (l4 * 4 + q) * 16 + l15] = acc[q];
      }
      __syncthreads();
      if (p2kh == 0) {
        const int lc = p2nt * 16 + l15;
#pragma unroll
        for (int q = 0; q < 4; ++q) {
          const int row = l4 * 4 + q;
          const float dot = acc[q] + red[p2nt * 256 + row * 16 + l15];
          float pre = dot + bfu2f(c2u[q]);
          pre = fminf(15.f, fmaxf(-15.f, pre));
          const float e = __expf(2.f * pre);
          const float th = (e - 1.f) / (e + 1.f);
          const float z = z_sh[row * 32 + lc];
          const float hold = hown[row * 32 + lc];
          const float hnew = (1.f - z) * hold + z * th;
          hown[row * 32 + lc] = hnew;
          h_buf[((g * 16 + row) << 9) + j * 32 + lc] = f2bf(hnew);
          if (tt == Tc - 1) h_state[((g * 16 + row) << 9) + j * 32 + lc] = hnew;
        }
      }
    }
    if (group_barrier(ctr, (++nbar) * 16, tid, &s_dead)) break;
  }
}

// ---------------------------------------------------------------- FC
__global__ __launch_bounds__(256) void fc_kernel(
    const float* __restrict__ h, const float* __restrict__ Wfc,
    const float* __restrict__ bfc, float* __restrict__ logits)
{
  __shared__ float hsh[16][520];
  const int tid = threadIdx.x;
  const int by = blockIdx.y;
  {
    const int r = tid >> 4, seg = tid & 15;
    const float* src = &h[(size_t)(by * 16 + r) * 512 + seg * 32];
#pragma unroll
    for (int i = 0; i < 8; ++i) {
      float4 v = *(const float4*)&src[i * 4];
      v.x = fmaxf(v.x, 0.f); v.y = fmaxf(v.y, 0.f);
      v.z = fmaxf(v.z, 0.f); v.w = fmaxf(v.w, 0.f);
      *(float4*)&hsh[r][seg * 32 + i * 4] = v;
    }
  }
  __syncthreads();
  const int c = tid & 63, rq = tid >> 6;
  const int gc = blockIdx.x * 64 + c;
  if (gc >= 1000) return;
  float acc0 = 0.f, acc1 = 0.f, acc2 = 0.f, acc3 = 0.f;
  for (int k = 0; k < 512; ++k) {
    const float w = Wfc[(size_t)k * 1000 + gc];
    acc0 += hsh[rq * 4 + 0][k] * w;
    acc1 += hsh[rq * 4 + 1][k] * w;
    acc2 += hsh[rq * 4 + 2][k] * w;
    acc3 += hsh[rq * 4 + 3][k] * w;
  }
  const float bv = bfc[gc];
  const int r0 = by * 16 + rq * 4;
  logits[(size_t)(r0 + 0) * 1000 + gc] = acc0 + bv;
  logits[(size_t)(r0 + 1) * 1000 + gc] = acc1 + bv;
  logits[(size_t)(r0 + 2) * 1000 + gc] = acc2 + bv;
  logits[(size_t)(r0 + 3) * 1000 + gc] = acc3 + bv;
}

// ---------------------------------------------------------------- log_softmax over batch
__global__ __launch_bounds__(256) void lsm_kernel(const float* __restrict__ logits,
                                                  float* __restrict__ out)
{
  const int c = blockIdx.x, tid = threadIdx.x;
  const int wid = tid >> 6, lane = tid & 63;
  __shared__ float red[8];
  const float v = logits[(size_t)tid * 1000 + c];
  float m = v;
#pragma unroll
  for (int o = 32; o >= 1; o >>= 1) m = fmaxf(m, __shfl_xor(m, o));
  if (lane == 0) red[wid] = m;
  __syncthreads();
  m = fmaxf(fmaxf(red[0], red[1]), fmaxf(red[2], red[3]));
  float s = __expf(v - m);
#pragma unroll
  for (int o = 32; o >= 1; o >>= 1) s += __shfl_xor(s, o);
  if (lane == 0) red[4 + wid] = s;
  __syncthreads();
  s = red[4] + red[5] + red[6] + red[7];
  out[(size_t)tid * 1000 + c] = (v - m) - __logf(s);
}

// ---------------------------------------------------------------- launch
extern "C" void kernel_launch(void* const* d_in, const int* in_sizes, int n_in,
                              void* d_out, int out_size, void* d_ws, size_t ws_size,
                              hipStream_t stream) {
  (void)in_sizes; (void)n_in; (void)out_size;
  const float* x   = (const float*)d_in[0];
  const float* Wz  = (const float*)d_in[1];
  const float* bz  = (const float*)d_in[2];
  const float* Uz  = (const float*)d_in[3];
  const float* buz = (const float*)d_in[4];
  const float* Wr  = (const float*)d_in[5];
  const float* br  = (const float*)d_in[6];
  const float* Ur  = (const float*)d_in[7];
  const float* bur = (const float*)d_in[8];
  const float* Wh  = (const float*)d_in[9];
  const float* bh  = (const float*)d_in[10];
  const float* Uh  = (const float*)d_in[11];
  const float* buh = (const float*)d_in[12];
  const float* Wfc = (const float*)d_in[13];
  const float* bfc = (const float*)d_in[14];
  float* out = (float*)d_out;
  char* ws = (char*)d_ws;

  ushort_t* UT     = (ushort_t*)(ws + 0);        // 1572864 B
  ushort_t* WT     = (ushort_t*)(ws + 1572864);  // 1572864 B
  float*    gbias  = (float*)(ws + 3145728);     // 6144 B
  ushort_t* h_buf  = (ushort_t*)(ws + 3151872);  // 262144 B
  ushort_t* rh_buf = (ushort_t*)(ws + 3414016);  // 262144 B
  float*    hstate = (float*)(ws + 3676160);     // 524288 B
  float*    logits = (float*)(ws + 4200448);     // 1024000 B (256x1000)
  uint_t*   bars   = (uint_t*)(ws + 5224448);    // 4096 B (16 groups x 256B)
  ushort_t* gates  = (ushort_t*)(ws + 5228544);  // Tc*256*1536*2 B

  const size_t fixed = 5228544;
  const size_t per_step = (size_t)256 * 1536 * 2;
  int Tc_max = 2048;
  if (ws_size < fixed + (size_t)2048 * per_step) {
    const size_t avail = (ws_size > fixed) ? (ws_size - fixed) : 0;
    Tc_max = (int)(avail / per_step);
    Tc_max &= ~15;
    if (Tc_max < 16) Tc_max = 16;
  }

  prep_kernel<<<3072, 256, 0, stream>>>(Wz, Wr, Wh, Uz, Ur, Uh,
                                        bz, buz, br, bur, bh, buh, UT, WT, gbias);

  int done = 0;
  while (done < 2048) {
    const int Tc = (2048 - done < Tc_max) ? (2048 - done) : Tc_max;
    const int mtiles = Tc * 4;  // Tc*256/64
    gate_gemm<<<mtiles, 256, 0, stream>>>(x + (size_t)done * 256 * 512, WT, gbias, gates, mtiles);
    hipMemsetAsync(bars, 0, 4096, stream);
    gru_rec<<<256, 256, 0, stream>>>(UT, gates, h_buf, rh_buf, hstate, bars, Tc, done == 0 ? 1 : 0);
    done += Tc;
  }
  fc_kernel<<<dim3(16, 16), 256, 0, stream>>>(hstate, Wfc, bfc, logits);
  lsm_kernel<<<1000, 256, 0, stream>>>(logits, out);
}

// Round 17
// 9867.541 us; speedup vs baseline: 1.1529x; 1.1529x over previous
//
#include <hip/hip_runtime.h>

// CustomRNN (GRU, SEQ=2048, B=256, D=512) + FC(1000) + log_softmax over batch axis.
//
// FINAL CONFIG (= R15, best measured: 9.92 ms total, gru_rec 8.22 ms).
//   gru_rec: persistent, 256 blocks = 16 groups x 16 col-slice blocks (XCD co-located),
//   U register-resident, h/rh via XCD-shared L2 (sc0), atomic-RMW group barrier
//   (the ONLY correct primitive class: load-polling fails, R4-R6), plain-load gate
//   prefetch at phase-2, stage rotation j*64. Floor: 2 barriers/step x ~1.5us fixed
//   atomic RT+skew latency (7 structural experiments all neutral-or-worse).
//   gate_gemm: 128x128 MFMA tiles + 8x12 XCD-aligned supertile.

typedef unsigned short ushort_t;
typedef unsigned int uint_t;
typedef __bf16 bf16_t;
typedef bf16_t bf16x8 __attribute__((ext_vector_type(8)));
typedef float f32x4 __attribute__((ext_vector_type(4)));
typedef uint_t u32x4 __attribute__((ext_vector_type(4)));

__device__ __forceinline__ ushort_t f2bf(float f) {
  uint_t u = __float_as_uint(f);
  u += 0x7FFFu + ((u >> 16) & 1u);   // round-to-nearest-even
  return (ushort_t)(u >> 16);
}
__device__ __forceinline__ float bfu2f(uint_t h) { return __uint_as_float(h << 16); }

// TCC atomic add WITH return (waits). RMW -> always served coherently at the TCC.
__device__ __forceinline__ uint_t atom_add_ret(uint_t* p, uint_t v) {
  uint_t old;
  asm volatile("global_atomic_add %0, %1, %2, off sc0\n\t"
               "s_waitcnt vmcnt(0)"
               : "=v"(old) : "v"(p), "v"(v) : "memory");
  return old;
}
// Fire-and-forget atomic add (no return -> no wait).
__device__ __forceinline__ void atom_add_noret(uint_t* p, uint_t v) {
  asm volatile("global_atomic_add %0, %1, off" :: "v"(p), "v"(v) : "memory");
}

// ---------------------------------------------------------------- prep
__global__ __launch_bounds__(256) void prep_kernel(
    const float* __restrict__ Wz, const float* __restrict__ Wr, const float* __restrict__ Wh,
    const float* __restrict__ Uz, const float* __restrict__ Ur, const float* __restrict__ Uh,
    const float* __restrict__ bz, const float* __restrict__ buz,
    const float* __restrict__ br, const float* __restrict__ bur,
    const float* __restrict__ bh, const float* __restrict__ buh,
    ushort_t* __restrict__ UT, ushort_t* __restrict__ WT, float* __restrict__ gbias)
{
  const int idx = blockIdx.x * 256 + threadIdx.x;  // exactly 786432 threads
  {
    const int gate = idx >> 18, n = (idx >> 9) & 511, k = idx & 511;
    const float* U = (gate == 0) ? Uz : (gate == 1 ? Ur : Uh);
    UT[idx] = f2bf(U[k * 512 + n]);                 // UT[gate][n][k] = U[k][n]
  }
  {
    const int n = idx >> 9, k = idx & 511;
    const int gate = n >> 9, nn = n & 511;
    const float* W = (gate == 0) ? Wz : (gate == 1 ? Wr : Wh);
    WT[idx] = f2bf(W[k * 512 + nn]);                // WT[n][k] = W[k][n]
  }
  if (idx < 1536) {
    const int gate = idx >> 9, nn = idx & 511;
    gbias[idx] = (gate == 0) ? (bz[nn] + buz[nn])
               : (gate == 1) ? (br[nn] + bur[nn])
                             : (bh[nn] + buh[nn]);
  }
}

// ---------------------------------------------------------------- gate GEMM
__global__ __launch_bounds__(256) void gate_gemm(
    const float* __restrict__ x,
    const ushort_t* __restrict__ WT,     // [1536][512] (n-major)
    const float* __restrict__ gbias,
    ushort_t* __restrict__ gout,         // [M][1536]
    int mtiles)
{
  __shared__ ushort_t A_sh[128 * 72];
  __shared__ ushort_t B_sh[128 * 72];
  const int bid = blockIdx.x;
  int mt, nt;
  if ((mtiles & 7) == 0) {
    // supertile 8 mtiles x 12 ntiles, XCD-aligned: r = nt*8 + mt  ->  bid%8 = mt%8.
    const int sb = bid / 96;
    const int r = bid - sb * 96;
    mt = sb * 8 + (r & 7);
    nt = r >> 3;
  } else {
    mt = bid / 12;
    nt = bid - mt * 12;
  }
  const int mrow0 = mt * 128;
  const int ncol0 = nt * 128;
  const int tid = threadIdx.x;
  const int wid = tid >> 6;
  const int lane = tid & 63;
  const int wm = wid >> 1, wn = wid & 1;
  const int l15 = lane & 15, l4 = lane >> 4;

  const f32x4 vzero = {0.f, 0.f, 0.f, 0.f};
  f32x4 acc[4][4];
#pragma unroll
  for (int m = 0; m < 4; ++m)
#pragma unroll
    for (int n = 0; n < 4; ++n) acc[m][n] = vzero;

  const int ar = tid >> 4, ak = tid & 15;
  const int bn = tid >> 3, bk = tid & 7;

  for (int ks = 0; ks < 8; ++ks) {
    if (ks) __syncthreads();
    const int k0 = ks * 64;
#pragma unroll
    for (int p = 0; p < 8; ++p) {
      const int r = p * 16 + ar;
      const float4 v = *(const float4*)&x[(size_t)(mrow0 + r) * 512 + (k0 + ak * 4)];
      ushort4 hv;
      hv.x = f2bf(v.x); hv.y = f2bf(v.y); hv.z = f2bf(v.z); hv.w = f2bf(v.w);
      *(ushort4*)&A_sh[r * 72 + ak * 4] = hv;
    }
#pragma unroll
    for (int p = 0; p < 4; ++p) {
      const int n = p * 32 + bn;
      *(uint4*)&B_sh[n * 72 + bk * 8] =
          *(const uint4*)&WT[(size_t)(ncol0 + n) * 512 + (k0 + bk * 8)];
    }
    __syncthreads();
#pragma unroll
    for (int kk = 0; kk < 2; ++kk) {
      bf16x8 a[4], b[4];
#pragma unroll
      for (int m = 0; m < 4; ++m)
        a[m] = *(const bf16x8*)&A_sh[(wm * 64 + m * 16 + l15) * 72 + kk * 32 + l4 * 8];
#pragma unroll
      for (int n = 0; n < 4; ++n)
        b[n] = *(const bf16x8*)&B_sh[(wn * 64 + n * 16 + l15) * 72 + kk * 32 + l4 * 8];
#pragma unroll
      for (int m = 0; m < 4; ++m)
#pragma unroll
        for (int n = 0; n < 4; ++n)
          acc[m][n] = __builtin_amdgcn_mfma_f32_16x16x32_bf16(a[m], b[n], acc[m][n], 0, 0, 0);
    }
  }
#pragma unroll
  for (int n = 0; n < 4; ++n) {
    const int gcol = ncol0 + wn * 64 + n * 16 + l15;
    const float bv = gbias[gcol];
#pragma unroll
    for (int m = 0; m < 4; ++m) {
      const int grow = mrow0 + wm * 64 + m * 16 + l4 * 4;
#pragma unroll
      for (int q = 0; q < 4; ++q)
        gout[(size_t)(grow + q) * 1536 + gcol] = f2bf(acc[m][n][q] + bv);
    }
  }
}

// ---------------------------------------------------------------- XCD-local group barrier
// Monotone counter; arrival = non-blocking add, wait = poll RMW until ctr >= 16*n.
__device__ __forceinline__ bool group_barrier(uint_t* ctr, uint_t target, int tid, int* s_dead) {
  asm volatile("s_waitcnt vmcnt(0)" ::: "memory");  // own stores committed to L2
  __syncthreads();                                   // all waves drained
  if (tid == 0) {
    atom_add_noret(ctr, 1u);
    int cnt = 0;
    for (;;) {
      const uint_t seen = atom_add_ret(ctr, 0u);     // RMW -> always served at TCC
      if (seen >= target) break;
      __builtin_amdgcn_s_sleep(1);
      if (++cnt > (1 << 15)) { *s_dead = 1; break; } // co-location broken: fast-fail
    }
  }
  __syncthreads();
  return *s_dead != 0;
}

// Stage a [16 rows][512] bf16 tile (16 KB) from global (shared L2) into LDS.
// sc0 loads bypass the (possibly stale) L1; ends with vmcnt(0).
// Chunk index rotated by j*64 (spread first-touch lines across the group).
__device__ __forceinline__ void stage16x512(const ushort_t* __restrict__ src, int g, int j,
                                            ushort_t* dst_lds, int tid) {
  const ushort_t* p[4];
  int ridx[4];
#pragma unroll
  for (int k = 0; k < 4; ++k) {
    const int idx = (tid + (k << 8) + j * 64) & 1023;
    ridx[k] = idx;
    const int r = idx >> 6, kc = idx & 63;
    p[k] = src + (((g * 16 + r) << 9) + kc * 8);
  }
  u32x4 v0, v1, v2, v3;
  asm volatile(
      "global_load_dwordx4 %0, %4, off sc0\n\t"
      "global_load_dwordx4 %1, %5, off sc0\n\t"
      "global_load_dwordx4 %2, %6, off sc0\n\t"
      "global_load_dwordx4 %3, %7, off sc0\n\t"
      "s_waitcnt vmcnt(0)"
      : "=&v"(v0), "=&v"(v1), "=&v"(v2), "=&v"(v3)
      : "v"(p[0]), "v"(p[1]), "v"(p[2]), "v"(p[3])
      : "memory");
#pragma unroll
  for (int k = 0; k < 4; ++k) {
    const int r = ridx[k] >> 6, kc = ridx[k] & 63;
    *(u32x4*)&dst_lds[r * 520 + kc * 8] = (k == 0) ? v0 : (k == 1) ? v1 : (k == 2) ? v2 : v3;
  }
}

// ---------------------------------------------------------------- persistent GRU recurrence
__global__ __launch_bounds__(256, 1) void gru_rec(
    const ushort_t* __restrict__ UT,     // [3][512 n][512 k] bf16
    const ushort_t* __restrict__ gates,  // [Tc][256][1536] bf16
    ushort_t* __restrict__ h_buf,        // [256][512] bf16
    ushort_t* __restrict__ rh_buf,       // [256][512] bf16
    float* __restrict__ h_state,         // [256][512] fp32
    uint_t* __restrict__ bars,
    int Tc, int first)
{
  __shared__ ushort_t h_st[16 * 520];
  __shared__ float z_sh[512];
  __shared__ float hown[512];
  __shared__ float red[512];
  __shared__ int s_dead;

  const int tid = threadIdx.x;
  const int bid = blockIdx.x;
  const int g = bid & 15;
  const int j = bid >> 4;
  const int wid = tid >> 6;
  const int lane = tid & 63;
  const int l15 = lane & 15;
  const int l4 = lane >> 4;
  if (tid == 0) s_dead = 0;

  uint_t* ctr = bars + g * 64;          // one counter per group, own cacheline
  uint_t nbar = 0;

  const int p1gate = wid >> 1;  // phase1: waves 0,1 -> z ; waves 2,3 -> r
  const int p1nt = wid & 1;
  const int p2nt = wid >> 1;    // phase2 subtile
  const int p2kh = wid & 1;     // phase2 K half

  // U fragments persistent in registers
  bf16x8 UB[16];
  {
    const size_t base = (size_t)((p1gate << 9) + j * 32 + p1nt * 16 + l15) * 512 + (size_t)(l4 * 8);
#pragma unroll
    for (int kk = 0; kk < 16; ++kk) UB[kk] = *(const bf16x8*)&UT[base + (size_t)kk * 32];
  }
  bf16x8 UH[8];
  {
    const size_t base = (size_t)(1024 + j * 32 + p2nt * 16 + l15) * 512 + (size_t)(p2kh * 256 + l4 * 8);
#pragma unroll
    for (int kk = 0; kk < 8; ++kk) UH[kk] = *(const bf16x8*)&UT[base + (size_t)kk * 32];
  }

  if (first) {
    for (int i = tid; i < 512; i += 256) {
      const int r = i >> 5, c = i & 31;
      h_buf[((g * 16 + r) << 9) + j * 32 + c] = 0;
      hown[i] = 0.f;
    }
  } else {
    for (int i = tid; i < 512; i += 256) {
      const int r = i >> 5, c = i & 31;
      hown[i] = h_state[((g * 16 + r) << 9) + j * 32 + c];
    }
  }
  if (group_barrier(ctr, (++nbar) * 16, tid, &s_dead)) return;

  const int colg1 = j * 32 + p1nt * 16 + l15;
  const int colg2 = j * 32 + p2nt * 16 + l15;

  // gate pipeline: n* prefetched as PLAIN compiler-tracked loads at phase-2 start
  // of the previous step; copied to c* at phase-1 top (compiler inserts the wait).
  uint_t c1u[4], c2u[4], n1u[4], n2u[4];
  {
    const size_t gb = (size_t)(g * 16) * 1536;
#pragma unroll
    for (int q = 0; q < 4; ++q) {
      n1u[q] = gates[gb + (size_t)(l4 * 4 + q) * 1536 + (p1gate << 9) + colg1];
      n2u[q] = gates[gb + (size_t)(l4 * 4 + q) * 1536 + 1024 + colg2];
    }
  }

  for (int tt = 0; tt < Tc; ++tt) {
    // ---- phase 1: z, r from h
    stage16x512(h_buf, g, j, h_st, tid);
    __syncthreads();
#pragma unroll
    for (int q = 0; q < 4; ++q) { c1u[q] = n1u[q]; c2u[q] = n2u[q]; }
    {
      const ushort_t* ap = &h_st[l15 * 520 + l4 * 8];
      f32x4 a0 = {0.f, 0.f, 0.f, 0.f}, a1 = {0.f, 0.f, 0.f, 0.f};
#pragma unroll
      for (int kk = 0; kk < 16; kk += 2) {
        a0 = __builtin_amdgcn_mfma_f32_16x16x32_bf16(*(const bf16x8*)(ap + kk * 32), UB[kk], a0, 0, 0, 0);
        a1 = __builtin_amdgcn_mfma_f32_16x16x32_bf16(*(const bf16x8*)(ap + kk * 32 + 32), UB[kk + 1], a1, 0, 0, 0);
      }
      const f32x4 acc = a0 + a1;
      const int lc = p1nt * 16 + l15;
#pragma unroll
      for (int q = 0; q < 4; ++q) {
        const int row = l4 * 4 + q;
        const float pre = acc[q] + bfu2f(c1u[q]);
        const float s = 1.f / (1.f + __expf(-pre));
        if (p1gate == 0) z_sh[row * 32 + lc] = s;
        else rh_buf[((g * 16 + row) << 9) + j * 32 + lc] = f2bf(s * hown[row * 32 + lc]);
      }
    }
    if (group_barrier(ctr, (++nbar) * 16, tid, &s_dead)) break;

    // ---- phase 2: h~ from (r*h), h update
    stage16x512(rh_buf, g, j, h_st, tid);
    __syncthreads();
    // prefetch next step's gates NOW (plain loads): they complete under the MFMA /
    // epilogue, so the pre-barrier vmcnt(0) and the poll carry no outstanding loads.
    if (tt + 1 < Tc) {
      const size_t gb = (size_t)((size_t)(tt + 1) * 256 + g * 16) * 1536;
#pragma unroll
      for (int q = 0; q < 4; ++q) {
        n1u[q] = gates[gb + (size_t)(l4 * 4 + q) * 1536 + (p1gate << 9) + colg1];
        n2u[q] = gates[gb + (size_t)(l4 * 4 + q) * 1536 + 1024 + colg2];
      }
    }
    {
      const ushort_t* ap = &h_st[l15 * 520 + p2kh * 256 + l4 * 8];
      f32x4 a0 = {0.f, 0.f, 0.f, 0.f}, a1 = {0.f, 0.f, 0.f, 0.f};
#pragma unroll
      for (int kk = 0; kk < 8; kk += 2) {
        a0 = __builtin_amdgcn_mfma_f32_16x16x32_bf16(*(const bf16x8*)(ap + kk * 32), UH[kk], a0, 0, 0, 0);
        a1 = __builtin_amdgcn_mfma_f32_16x16x32_bf16(*(const bf16x8*)(ap + kk * 32 + 32), UH[kk + 1], a1, 0, 0, 0);
      }
      const f32x4 acc = a0 + a1;
      if (p2kh == 1) {
#pragma unroll
        for (int q = 0; q < 4; ++q) red[p2nt * 256 + (l4 * 4 + q) * 16 + l15] = acc[q];
      }
      __syncthreads();
      if (p2kh == 0) {
        const int lc = p2nt * 16 + l15;
#pragma unroll
        for (int q = 0; q < 4; ++q) {
          const int row = l4 * 4 + q;
          const float dot = acc[q] + red[p2nt * 256 + row * 16 + l15];
          float pre = dot + bfu2f(c2u[q]);
          pre = fminf(15.f, fmaxf(-15.f, pre));
          const float e = __expf(2.f * pre);
          const float th = (e - 1.f) / (e + 1.f);
          const float z = z_sh[row * 32 + lc];
          const float hold = hown[row * 32 + lc];
          const float hnew = (1.f - z) * hold + z * th;
          hown[row * 32 + lc] = hnew;
          h_buf[((g * 16 + row) << 9) + j * 32 + lc] = f2bf(hnew);
          if (tt == Tc - 1) h_state[((g * 16 + row) << 9) + j * 32 + lc] = hnew;
        }
      }
    }
    if (group_barrier(ctr, (++nbar) * 16, tid, &s_dead)) break;
  }
}

// ---------------------------------------------------------------- FC
__global__ __launch_bounds__(256) void fc_kernel(
    const float* __restrict__ h, const float* __restrict__ Wfc,
    const float* __restrict__ bfc, float* __restrict__ logits)
{
  __shared__ float hsh[16][520];
  const int tid = threadIdx.x;
  const int by = blockIdx.y;
  {
    const int r = tid >> 4, seg = tid & 15;
    const float* src = &h[(size_t)(by * 16 + r) * 512 + seg * 32];
#pragma unroll
    for (int i = 0; i < 8; ++i) {
      float4 v = *(const float4*)&src[i * 4];
      v.x = fmaxf(v.x, 0.f); v.y = fmaxf(v.y, 0.f);
      v.z = fmaxf(v.z, 0.f); v.w = fmaxf(v.w, 0.f);
      *(float4*)&hsh[r][seg * 32 + i * 4] = v;
    }
  }
  __syncthreads();
  const int c = tid & 63, rq = tid >> 6;
  const int gc = blockIdx.x * 64 + c;
  if (gc >= 1000) return;
  float acc0 = 0.f, acc1 = 0.f, acc2 = 0.f, acc3 = 0.f;
  for (int k = 0; k < 512; ++k) {
    const float w = Wfc[(size_t)k * 1000 + gc];
    acc0 += hsh[rq * 4 + 0][k] * w;
    acc1 += hsh[rq * 4 + 1][k] * w;
    acc2 += hsh[rq * 4 + 2][k] * w;
    acc3 += hsh[rq * 4 + 3][k] * w;
  }
  const float bv = bfc[gc];
  const int r0 = by * 16 + rq * 4;
  logits[(size_t)(r0 + 0) * 1000 + gc] = acc0 + bv;
  logits[(size_t)(r0 + 1) * 1000 + gc] = acc1 + bv;
  logits[(size_t)(r0 + 2) * 1000 + gc] = acc2 + bv;
  logits[(size_t)(r0 + 3) * 1000 + gc] = acc3 + bv;
}

// ---------------------------------------------------------------- log_softmax over batch
__global__ __launch_bounds__(256) void lsm_kernel(const float* __restrict__ logits,
                                                  float* __restrict__ out)
{
  const int c = blockIdx.x, tid = threadIdx.x;
  const int wid = tid >> 6, lane = tid & 63;
  __shared__ float red[8];
  const float v = logits[(size_t)tid * 1000 + c];
  float m = v;
#pragma unroll
  for (int o = 32; o >= 1; o >>= 1) m = fmaxf(m, __shfl_xor(m, o));
  if (lane == 0) red[wid] = m;
  __syncthreads();
  m = fmaxf(fmaxf(red[0], red[1]), fmaxf(red[2], red[3]));
  float s = __expf(v - m);
#pragma unroll
  for (int o = 32; o >= 1; o >>= 1) s += __shfl_xor(s, o);
  if (lane == 0) red[4 + wid] = s;
  __syncthreads();
  s = red[4] + red[5] + red[6] + red[7];
  out[(size_t)tid * 1000 + c] = (v - m) - __logf(s);
}

// ---------------------------------------------------------------- launch
extern "C" void kernel_launch(void* const* d_in, const int* in_sizes, int n_in,
                              void* d_out, int out_size, void* d_ws, size_t ws_size,
                              hipStream_t stream) {
  (void)in_sizes; (void)n_in; (void)out_size;
  const float* x   = (const float*)d_in[0];
  const float* Wz  = (const float*)d_in[1];
  const float* bz  = (const float*)d_in[2];
  const float* Uz  = (const float*)d_in[3];
  const float* buz = (const float*)d_in[4];
  const float* Wr  = (const float*)d_in[5];
  const float* br  = (const float*)d_in[6];
  const float* Ur  = (const float*)d_in[7];
  const float* bur = (const float*)d_in[8];
  const float* Wh  = (const float*)d_in[9];
  const float* bh  = (const float*)d_in[10];
  const float* Uh  = (const float*)d_in[11];
  const float* buh = (const float*)d_in[12];
  const float* Wfc = (const float*)d_in[13];
  const float* bfc = (const float*)d_in[14];
  float* out = (float*)d_out;
  char* ws = (char*)d_ws;

  ushort_t* UT     = (ushort_t*)(ws + 0);        // 1572864 B
  ushort_t* WT     = (ushort_t*)(ws + 1572864);  // 1572864 B
  float*    gbias  = (float*)(ws + 3145728);     // 6144 B
  ushort_t* h_buf  = (ushort_t*)(ws + 3151872);  // 262144 B
  ushort_t* rh_buf = (ushort_t*)(ws + 3414016);  // 262144 B
  float*    hstate = (float*)(ws + 3676160);     // 524288 B
  float*    logits = (float*)(ws + 4200448);     // 1024000 B (256x1000)
  uint_t*   bars   = (uint_t*)(ws + 5224448);    // 4096 B (16 groups x 256B)
  ushort_t* gates  = (ushort_t*)(ws + 5228544);  // Tc*256*1536*2 B

  const size_t fixed = 5228544;
  const size_t per_step = (size_t)256 * 1536 * 2;
  int Tc_max = 2048;
  if (ws_size < fixed + (size_t)2048 * per_step) {
    const size_t avail = (ws_size > fixed) ? (ws_size - fixed) : 0;
    Tc_max = (int)(avail / per_step);
    Tc_max &= ~15;             // keeps mtiles % 8 == 0 for the XCD-aligned supertile
    if (Tc_max < 16) Tc_max = 16;
  }

  prep_kernel<<<3072, 256, 0, stream>>>(Wz, Wr, Wh, Uz, Ur, Uh,
                                        bz, buz, br, bur, bh, buh, UT, WT, gbias);

  int done = 0;
  while (done < 2048) {
    const int Tc = (2048 - done < Tc_max) ? (2048 - done) : Tc_max;
    const int mtiles = Tc * 2;  // Tc*256/128
    gate_gemm<<<mtiles * 12, 256, 0, stream>>>(x + (size_t)done * 256 * 512, WT, gbias, gates, mtiles);
    hipMemsetAsync(bars, 0, 4096, stream);
    gru_rec<<<256, 256, 0, stream>>>(UT, gates, h_buf, rh_buf, hstate, bars, Tc, done == 0 ? 1 : 0);
    done += Tc;
  }
  fc_kernel<<<dim3(16, 16), 256, 0, stream>>>(hstate, Wfc, bfc, logits);
  lsm_kernel<<<1000, 256, 0, stream>>>(logits, out);
}